// Round 4
// baseline (160.391 us; speedup 1.0000x reference)
//
#include <hip/hip_runtime.h>
#include <hip/hip_bf16.h>

// B,C,H,W = 4,64,64,64 ; N = 4096 ; d = 8
#define BB 4
#define CC 64
#define NN 4096

typedef __attribute__((ext_vector_type(8))) short short8;
typedef __attribute__((ext_vector_type(4))) float f32x4;

__device__ inline ushort f2bf(float x) {                 // RNE float->bf16
    unsigned u = __float_as_uint(x);
    return (ushort)((u + 0x7fff + ((u >> 16) & 1)) >> 16);
}
__device__ inline float bf2f(ushort h) { return __uint_as_float(((unsigned)h) << 16); }

// ws layout (ushort):
//   qTp [B][N][32] : q0..q7, q0h,q1h,q0l,q1l, 0*20               (1 MB)
//   kTp [B][N][32] : k0..k7, col,row,col,row, 0*20               (1 MB)
//   vsw [B][64t][2s*4g][64 lane][8 jj]  B-frag swizzled bf16 V   (2 MB)
//   kmax [B][8] fp32-as-uint (atomicMax of |bf16 k_d|), memset 0 first

// ---------------------------------------------------------------------------
// Kernel 1: QKV projection. 256 blocks = (b, t=64-pixel tile), 512 threads.
// og = tid>>6 (wave-uniform): 8 v-rows each + 2 q-rows (og<4) or 2 k-rows.
// Wave-uniform weight rows -> s_load; x loads 256B coalesced, L1-shared.
// LDS transpose (padded strides) -> fully coalesced uint4 tile stores.
// ---------------------------------------------------------------------------
__global__ __launch_bounds__(512) void qkv_kernel(
    const float* __restrict__ x,
    const float* __restrict__ Wq, const float* __restrict__ bq,
    const float* __restrict__ Wk, const float* __restrict__ bk,
    const float* __restrict__ Wv, const float* __restrict__ bv,
    ushort* __restrict__ qTp, ushort* __restrict__ kTp,
    ushort* __restrict__ vsw, unsigned* __restrict__ kmax)
{
    const int b = blockIdx.x >> 6, t = blockIdx.x & 63;
    const int tid = threadIdx.x, og = tid >> 6, px = tid & 63;
    const int n = t * 64 + px;

    __shared__ ushort vt[64 * 72];   // [ch][px], stride 72 halves (144B, 16B-mult)
    __shared__ ushort qt[64 * 40];   // [px][ch], stride 40 halves (80B)
    __shared__ ushort kt[64 * 40];

    // zero qt/kt (zero-padded channels 12..31)
    {
        unsigned* z1 = (unsigned*)qt;
        unsigned* z2 = (unsigned*)kt;
        for (int i = tid; i < 64 * 40 / 2; i += 512) { z1[i] = 0u; z2[i] = 0u; }
    }

    float av[8], a0, a1;
#pragma unroll
    for (int u = 0; u < 8; ++u) av[u] = bv[og * 8 + u];
    if (og < 4) { a0 = bq[og * 2]; a1 = bq[og * 2 + 1]; }
    else        { a0 = bk[(og - 4) * 2]; a1 = bk[(og - 4) * 2 + 1]; }

    {
        const float* xb   = x + (size_t)(b * CC) * NN + n;
        const float* wv0  = Wv + (og * 8) * CC;
        const float* wqk0 = (og < 4) ? (Wq + (og * 2) * CC) : (Wk + ((og - 4) * 2) * CC);
        for (int cb = 0; cb < 4; ++cb) {
            float xc[16];
#pragma unroll
            for (int u = 0; u < 16; ++u) xc[u] = xb[(size_t)(cb * 16 + u) * NN];
#pragma unroll
            for (int u = 0; u < 16; ++u) {
                const int c = cb * 16 + u;
                const float xx = xc[u];
#pragma unroll
                for (int e = 0; e < 8; ++e) av[e] += wv0[e * CC + c] * xx;
                a0 += wqk0[c] * xx;
                a1 += wqk0[CC + c] * xx;
            }
        }
    }
    __syncthreads();   // zero-fill complete

    // scatter into LDS
#pragma unroll
    for (int u = 0; u < 8; ++u) vt[(og * 8 + u) * 72 + px] = f2bf(av[u]);
    if (og < 4) {
        qt[px * 40 + og * 2]     = f2bf(a0);
        qt[px * 40 + og * 2 + 1] = f2bf(a1);
        if (og == 0) {   // rel-pos hi/lo split of q0,q1
            const ushort h0 = f2bf(a0), h1 = f2bf(a1);
            qt[px * 40 + 8]  = h0;
            qt[px * 40 + 9]  = h1;
            qt[px * 40 + 10] = f2bf(a0 - bf2f(h0));
            qt[px * 40 + 11] = f2bf(a1 - bf2f(h1));
        }
    } else {
        kt[px * 40 + (og - 4) * 2]     = f2bf(a0);
        kt[px * 40 + (og - 4) * 2 + 1] = f2bf(a1);
        if (og == 4) {   // fold channels: col, row, col, row (exact in bf16)
            const ushort hc = f2bf((float)px), hr = f2bf((float)t);
            kt[px * 40 + 8]  = hc;
            kt[px * 40 + 9]  = hr;
            kt[px * 40 + 10] = hc;
            kt[px * 40 + 11] = hr;
        }
        // per-batch |k_d| max (of the bf16-rounded values actually used)
        float m0 = fabsf(bf2f(f2bf(a0))), m1 = fabsf(bf2f(f2bf(a1)));
#pragma unroll
        for (int off = 1; off < 64; off <<= 1) {
            m0 = fmaxf(m0, __shfl_xor(m0, off, 64));
            m1 = fmaxf(m1, __shfl_xor(m1, off, 64));
        }
        if (px == 0) {
            atomicMax(kmax + b * 8 + (og - 4) * 2,     __float_as_uint(m0));
            atomicMax(kmax + b * 8 + (og - 4) * 2 + 1, __float_as_uint(m1));
        }
    }
    __syncthreads();

    // coalesced tile stores
    if (tid < 256) {
        const int p2 = tid >> 2, cg = tid & 3;
        *(uint4*)(qTp + ((size_t)(b * NN + t * 64 + p2)) * 32 + cg * 8) =
            *(const uint4*)(qt + p2 * 40 + cg * 8);
        *(uint4*)(kTp + ((size_t)(b * NN + t * 64 + p2)) * 32 + cg * 8) =
            *(const uint4*)(kt + p2 * 40 + cg * 8);
    }
    {
        // chunk tid = s*256 + g*64 + quad*16 + nn ; 16B per thread, contiguous
        const int s = tid >> 8, g = (tid >> 6) & 3, quad = (tid >> 4) & 3, nn = tid & 15;
        *(uint4*)(vsw + ((size_t)(b * 64 + t) * 512 + tid) * 8) =
            *(const uint4*)(vt + (g * 16 + nn) * 72 + (s * 4 + quad) * 8);
    }
}

// ---------------------------------------------------------------------------
// Kernel 2: single-pass MFMA attention with safe softmax bound.
// 512 blocks = (b, 32-query tile), 512 threads = 8 waves.
// Each wave: same 32 queries (2 B-frags), 8-way key split (8 tiles of 64).
// M~ = relmax + max(B1-20,0)+1 >= max folded score - 20; uniform e^-delta
// cancels in softmax. Barrier-free main loop; LDS ds_add_f32 combine.
// ---------------------------------------------------------------------------
__global__ __launch_bounds__(512, 4) void attn_kernel(
    const ushort* __restrict__ qTp, const ushort* __restrict__ kTp,
    const ushort* __restrict__ vsw, const unsigned* __restrict__ kmaxu,
    float* __restrict__ out)
{
    const int blk = blockIdx.x;
    const int b = blk >> 7, nq = (blk & 127) * 32;
    const int tid = threadIdx.x, wv = tid >> 6, lane = tid & 63;
    const int nn = lane & 15, quad = lane >> 4;

    __shared__ ushort Pbuf[8][32 * 72];   // per-wave P tiles, stride 72 halves
    __shared__ float  obuf[32 * 81];      // [q][81]: ch 0..63 = out, 64 = den

    for (int i = tid; i < 32 * 81; i += 512) obuf[i] = 0.f;

    // Q B-frags: lane holds channels quad*8..+8 of query (nq + qg*16 + nn)
    short8 qf[2];
    qf[0] = *(const short8*)(qTp + (size_t)(b * NN + nq + nn) * 32 + quad * 8);
    qf[1] = *(const short8*)(qTp + (size_t)(b * NN + nq + 16 + nn) * 32 + quad * 8);

    // ---- safe per-query softmax shift M~ ----
    float Mq[2];
    {
        const float* kmax = (const float*)kmaxu + b * 8;
#pragma unroll
        for (int qg = 0; qg < 2; ++qg) {
            float B1 = 0.f;   // valid on quad 0 (channels 0..7)
#pragma unroll
            for (int d = 0; d < 8; ++d) B1 += fabsf(bf2f((ushort)qf[qg][d])) * kmax[d];
            // valid on quad 1 (channels 8..11 = q0h,q1h,q0l,q1l)
            const float q0 = bf2f((ushort)qf[qg][0]) + bf2f((ushort)qf[qg][2]);
            const float q1 = bf2f((ushort)qf[qg][1]) + bf2f((ushort)qf[qg][3]);
            const float rel = fmaxf(q0 * 63.f, 0.f) + fmaxf(q1 * 63.f, 0.f);
            const float z  = (quad == 0) ? B1 : ((quad == 1) ? rel : 0.f);
            const float r1 = __shfl_xor(z, 16, 64);
            const float myB1  = (quad == 0) ? z : r1;
            const float myRel = (quad == 0) ? r1 : z;
            float f = myRel + fmaxf(myB1 - 20.f, 0.f) + 1.f;
            f = (quad < 2) ? f : 0.f;
            Mq[qg] = f + __shfl_xor(f, 32, 64);
        }
    }

    f32x4 acc[2][4];
#pragma unroll
    for (int qg = 0; qg < 2; ++qg)
#pragma unroll
        for (int g = 0; g < 4; ++g) acc[qg][g] = (f32x4){0.f, 0.f, 0.f, 0.f};
    float den[2] = {0.f, 0.f};

    ushort* Pw = Pbuf[wv];
    const ushort* kb  = kTp + (size_t)b * NN * 32;
    const ushort* vb0 = vsw + (size_t)b * 64 * 512 * 8;

    __syncthreads();   // obuf zeros visible before post-loop ds_add

    for (int it = 0; it < 8; ++it) {
        const int t = wv + it * 8;
        short8 kf[4];
#pragma unroll
        for (int kg = 0; kg < 4; ++kg)
            kf[kg] = *(const short8*)(kb + (size_t)(t * 64 + kg * 16 + nn) * 32 + quad * 8);

#pragma unroll
        for (int qg = 0; qg < 2; ++qg) {
#pragma unroll
            for (int kg = 0; kg < 4; ++kg) {
                f32x4 S = __builtin_amdgcn_mfma_f32_16x16x32_bf16(
                    kf[kg], qf[qg], (f32x4){0.f, 0.f, 0.f, 0.f}, 0, 0, 0);
                // lane = query nn ; regs = keys kg*16 + quad*4 .. +3
                const float w0 = __expf(S[0] - Mq[qg]);
                const float w1 = __expf(S[1] - Mq[qg]);
                const float w2 = __expf(S[2] - Mq[qg]);
                const float w3 = __expf(S[3] - Mq[qg]);
                union { __hip_bfloat162 h; unsigned u; } pa, pb;
                pa.h = __float22bfloat162_rn(make_float2(w0, w1));
                pb.h = __float22bfloat162_rn(make_float2(w2, w3));
                // denominator from the bf16-rounded weights (num/den consistent)
                den[qg] += __uint_as_float(pa.u << 16) + __uint_as_float(pa.u & 0xffff0000u)
                         + __uint_as_float(pb.u << 16) + __uint_as_float(pb.u & 0xffff0000u);
                uint2 pk; pk.x = pa.u; pk.y = pb.u;
                *(uint2*)(Pw + (qg * 16 + nn) * 72 + kg * 16 + quad * 4) = pk;
            }
        }
        // PV: A = P (b128 frags from LDS), B = swizzled V' (global, L2-hot)
        const ushort* vt0 = vb0 + (size_t)t * 512 * 8;
#pragma unroll
        for (int s = 0; s < 2; ++s) {
            const short8 af0 = *(const short8*)(Pw + (0 * 16 + nn) * 72 + s * 32 + quad * 8);
            const short8 af1 = *(const short8*)(Pw + (1 * 16 + nn) * 72 + s * 32 + quad * 8);
#pragma unroll
            for (int g = 0; g < 4; ++g) {
                const short8 vf = *(const short8*)(vt0 + (size_t)((s * 4 + g) * 64 + lane) * 8);
                acc[0][g] = __builtin_amdgcn_mfma_f32_16x16x32_bf16(af0, vf, acc[0][g], 0, 0, 0);
                acc[1][g] = __builtin_amdgcn_mfma_f32_16x16x32_bf16(af1, vf, acc[1][g], 0, 0, 0);
            }
        }
    }

    // ---- combine across the 8 key-split waves ----
#pragma unroll
    for (int qg = 0; qg < 2; ++qg) {
        float d = den[qg];
        d += __shfl_xor(d, 16, 64);
        d += __shfl_xor(d, 32, 64);
        if (lane < 16) atomicAdd(&obuf[(qg * 16 + lane) * 81 + 64], d);
    }
#pragma unroll
    for (int qg = 0; qg < 2; ++qg)
#pragma unroll
        for (int g = 0; g < 4; ++g)
#pragma unroll
            for (int r = 0; r < 4; ++r)
                atomicAdd(&obuf[(qg * 16 + quad * 4 + r) * 81 + g * 16 + nn], acc[qg][g][r]);
    __syncthreads();

    // epilogue: out[b][c][nq+q] ; lanes 0..31 = consecutive n (coalesced)
    {
        const int q = tid & 31, c0 = tid >> 5;
#pragma unroll
        for (int i = 0; i < 4; ++i) {
            const int c = c0 + i * 16;
            out[(size_t)(b * CC + c) * NN + nq + q] = obuf[q * 81 + c] / obuf[q * 81 + 64];
        }
    }
}

extern "C" void kernel_launch(void* const* d_in, const int* in_sizes, int n_in,
                              void* d_out, int out_size, void* d_ws, size_t ws_size,
                              hipStream_t stream) {
    const float* x  = (const float*)d_in[0];
    const float* Wq = (const float*)d_in[1];
    const float* bq = (const float*)d_in[2];
    const float* Wk = (const float*)d_in[3];
    const float* bk = (const float*)d_in[4];
    const float* Wv = (const float*)d_in[5];
    const float* bv = (const float*)d_in[6];
    float* out = (float*)d_out;

    ushort* ws  = (ushort*)d_ws;
    ushort* qTp = ws;                                     // B*N*32 halves
    ushort* kTp = qTp + (size_t)BB * NN * 32;             // B*N*32 halves
    ushort* vsw = kTp + (size_t)BB * NN * 32;             // B*64*512*8 halves
    unsigned* kmax = (unsigned*)(vsw + (size_t)BB * 64 * 512 * 8);  // B*8

    hipMemsetAsync(kmax, 0, BB * 8 * sizeof(unsigned), stream);
    qkv_kernel<<<BB * 64, 512, 0, stream>>>(x, Wq, bq, Wk, bk, Wv, bv, qTp, kTp, vsw, kmax);
    attn_kernel<<<BB * 128, 512, 0, stream>>>(qTp, kTp, vsw, kmax, out);
}